// Round 9
// baseline (106.652 us; speedup 1.0000x reference)
//
#include <hip/hip_runtime.h>
#include <math.h>

typedef _Float16 f16x8  __attribute__((ext_vector_type(8)));    // MFMA A/B operand (4 VGPRs)
typedef _Float16 h2v    __attribute__((ext_vector_type(2)));
typedef float    f32x16 __attribute__((ext_vector_type(16)));   // MFMA C/D operand (32x32)
typedef float    f32x4  __attribute__((ext_vector_type(4)));
typedef __fp16   h2a    __attribute__((ext_vector_type(2)));    // cvt_pkrtz result
typedef unsigned u32x4  __attribute__((ext_vector_type(4)));

#define WS    10
#define HID   32
#define BDIM  256
#define NWAVE 4
#define GN    32                  // points per group = MFMA N
#define T_LEN 4096
#define NGRP  (T_LEN / GN)        // 128 groups per row; 32 per wave

__device__ inline unsigned pack2u(float a, float b) {
    h2a t = __builtin_amdgcn_cvt_pkrtz(a, b);   // a -> low16, b -> high16
    return __builtin_bit_cast(unsigned, t);
}
__device__ inline unsigned relu2(unsigned u) {  // v_pk_max_f16 with 0
    h2v x = __builtin_bit_cast(h2v, u);
    h2v z = {(_Float16)0.0f, (_Float16)0.0f};
    return __builtin_bit_cast(unsigned, __builtin_elementwise_max(x, z));
}

// (256,4): regs <=128/lane -> 16 waves/CU -> all 1024 blocks co-resident
// (4 blocks/CU x 256 CU). No LDS, no barriers: pure TLP latency hiding.
__global__ __launch_bounds__(BDIM, 4)
void hurst_row(const float* __restrict__ returns,
               const float* __restrict__ W1, const float* __restrict__ b1,
               const float* __restrict__ W2, const float* __restrict__ b2,
               const float* __restrict__ W3, const float* __restrict__ b3,
               float* __restrict__ out)
{
    const int tid  = threadIdx.x;
    const int wid  = tid >> 6;
    const int lane = tid & 63;
    const int n    = lane & 31;    // MFMA m (A-row) / n (B/C col)
    const int hi   = lane >> 5;    // k-half (A/B) / row-half (C/D)
    const int permidx = (lane ^ 32) << 2;   // cross-half bpermute byte index

    // ---- bias / W3 in C-layout via dwordx4: row(r)=(r&3)+8(r>>2)+4hi ----
    f32x16 b1v, b2v, w3v;
    #pragma unroll
    for (int i = 0; i < 4; ++i) {
        const f32x4 v1 = ((const f32x4*)b1)[2 * i + hi];
        const f32x4 v2 = ((const f32x4*)b2)[2 * i + hi];
        const f32x4 v3 = ((const f32x4*)W3)[2 * i + hi];
        #pragma unroll
        for (int o = 0; o < 4; ++o) {
            b1v[4 * i + o] = v1[o];
            b2v[4 * i + o] = v2[o];
            w3v[4 * i + o] = v3[o];
        }
    }
    const float b3s = b3[0];

    // ---- A-frags. W2 rows permuted by phi(k)=swap(bit2,bit3): L1's C-layout
    // then IS L2's B-layout lane-locally (verified r6-r8, absmax 1.95e-3). ----
    f16x8 a1, a2lo, a2hi;
    #pragma unroll
    for (int jj = 0; jj < 8; ++jj) {
        const int k  = 8 * hi + jj;
        a1[jj] = (k < WS) ? (_Float16)W1[k * HID + n] : (_Float16)0.0f;   // W1^T, K 10->16 pad
        const int kf = (k & 3) | ((k & 4) << 1) | ((k & 8) >> 1);         // swap bits 2<->3
        a2lo[jj] = (_Float16)W2[kf * HID + n];
        a2hi[jj] = (_Float16)W2[(16 + kf) * HID + n];
    }

    const float* rptr = returns + (size_t)blockIdx.x * T_LEN;
    float*       optr = out     + (size_t)blockIdx.x * T_LEN;

    for (int g = wid; g < NGRP; g += NWAVE) {
        const int t  = g * GN + n;
        const int ws = (t >= WS) ? (t - WS) : 0;   // head points (t<10) reuse window 0

        // ---- X B-frag straight from global: lane's window bytes are contiguous.
        // hi=0: window elems 0..7 = rptr[ws..ws+7]; hi=1: elems 8,9 + zero-pad.
        // 4B-aligned only -> memcpy (unaligned-capable loads). L1-served:
        // adjacent lanes overlap by all but 4B.
        u32x4 xu;
        if (hi == 0) {
            float w8[8];
            __builtin_memcpy(w8, &rptr[ws], 32);
            xu[0] = pack2u(w8[0], w8[1]);
            xu[1] = pack2u(w8[2], w8[3]);
            xu[2] = pack2u(w8[4], w8[5]);
            xu[3] = pack2u(w8[6], w8[7]);
        } else {
            float w2[2];
            __builtin_memcpy(w2, &rptr[ws + 8], 8);
            xu[0] = pack2u(w2[0], w2[1]);
            xu[1] = 0u; xu[2] = 0u; xu[3] = 0u;    // k = 10..15 zero
        }
        const f16x8 xb = __builtin_bit_cast(f16x8, xu);

        // ---- L1: D1[j][n] = sum_k W1[k][j]*X[n][k]; bias rides the C-operand ----
        f32x16 d1 = __builtin_amdgcn_mfma_f32_32x32x16_f16(a1, xb, b1v, 0, 0, 0);

        // ---- relu+pack: lane-local pairs ARE the L2 B-operand (phi-permuted W2) ----
        u32x4 blo_u, bhi_u;
        #pragma unroll
        for (int i = 0; i < 4; ++i) {
            blo_u[i] = relu2(pack2u(d1[2 * i],     d1[2 * i + 1]));
            bhi_u[i] = relu2(pack2u(d1[8 + 2 * i], d1[9 + 2 * i]));
        }

        // ---- L2 (serial accumulate keeps regs <=128) ----
        f32x16 d2 = __builtin_amdgcn_mfma_f32_32x32x16_f16(
                        a2lo, __builtin_bit_cast(f16x8, blo_u), b2v, 0, 0, 0);
        d2 = __builtin_amdgcn_mfma_f32_32x32x16_f16(
                        a2hi, __builtin_bit_cast(f16x8, bhi_u), d2, 0, 0, 0);

        // ---- L3: per-lane partial over 16 rows + one cross-half reduce ----
        float acc = 0.0f;
        #pragma unroll
        for (int r = 0; r < 16; ++r)
            acc = fmaf(fmaxf(d2[r], 0.0f), w3v[r], acc);
        acc += __builtin_bit_cast(float,
                 __builtin_amdgcn_ds_bpermute(permidx, __builtin_bit_cast(int, acc)));

        // ---- sigmoid epilogue; 32 coalesced stores from half 0 ----
        const float o = 0.5f * __builtin_amdgcn_rcpf(1.0f + __expf(-(acc + b3s)));
        if (hi == 0)
            optr[t] = o;
    }
}

extern "C" void kernel_launch(void* const* d_in, const int* in_sizes, int n_in,
                              void* d_out, int out_size, void* d_ws, size_t ws_size,
                              hipStream_t stream) {
    const float* returns = (const float*)d_in[0];
    const float* W1      = (const float*)d_in[1];
    const float* b1      = (const float*)d_in[2];
    const float* W2      = (const float*)d_in[3];
    const float* b2      = (const float*)d_in[4];
    const float* W3      = (const float*)d_in[5];
    const float* b3      = (const float*)d_in[6];
    float* out = (float*)d_out;

    const int B = out_size / T_LEN;   // 1024

    dim3 grid(B, 1, 1);               // one block per batch row; fully co-resident
    dim3 block(BDIM, 1, 1);
    hurst_row<<<grid, block, 0, stream>>>(returns, W1, b1, W2, b2, W3, b3, out);
}

// Round 10
// 101.779 us; speedup vs baseline: 1.0479x; 1.0479x over previous
//
#include <hip/hip_runtime.h>
#include <math.h>

typedef _Float16 f16x8  __attribute__((ext_vector_type(8)));    // MFMA A/B operand (4 VGPRs)
typedef _Float16 h2v    __attribute__((ext_vector_type(2)));
typedef float    f32x16 __attribute__((ext_vector_type(16)));   // MFMA C/D operand (32x32)
typedef float    f32x4  __attribute__((ext_vector_type(4)));
typedef __fp16   h2a    __attribute__((ext_vector_type(2)));    // cvt_pkrtz result
typedef unsigned u32x4  __attribute__((ext_vector_type(4)));

#define WS    10
#define HID   32
#define BDIM  256
#define NWAVE 4
#define GN    32                  // points per group = MFMA N
#define T_LEN 4096
#define NGRP  (T_LEN / GN)        // 128 groups per row; 32 per wave

__device__ inline unsigned pack2u(float a, float b) {
    h2a t = __builtin_amdgcn_cvt_pkrtz(a, b);   // a -> low16, b -> high16
    return __builtin_bit_cast(unsigned, t);
}
__device__ inline unsigned relu2(unsigned u) {  // v_pk_max_f16 with 0
    h2v x = __builtin_bit_cast(h2v, u);
    h2v z = {(_Float16)0.0f, (_Float16)0.0f};
    return __builtin_bit_cast(unsigned, __builtin_elementwise_max(x, z));
}

// One block per batch row; all 1024 blocks co-resident at <=128 regs/lane.
// Entire MLP = 5 MFMAs/group: L1 (1) -> L2 (2) -> L3 (2, W3 broadcast across
// all A-rows so D[m][n] = out[n] for every m; bias b3 rides the C-init).
__global__ __launch_bounds__(BDIM, 4)
void hurst_row5(const float* __restrict__ returns,
                const float* __restrict__ W1, const float* __restrict__ b1,
                const float* __restrict__ W2, const float* __restrict__ b2,
                const float* __restrict__ W3, const float* __restrict__ b3,
                float* __restrict__ out)
{
    const int tid  = threadIdx.x;
    const int wid  = tid >> 6;
    const int lane = tid & 63;
    const int n    = lane & 31;    // MFMA m (A-row) / n (B/C col)
    const int hi   = lane >> 5;    // k-half (A/B) / row-half (C/D)

    // ---- bias C-operands in C-layout: row(r)=(r&3)+8(r>>2)+4hi ----
    f32x16 b1v, b2v, b3v;
    #pragma unroll
    for (int i = 0; i < 4; ++i) {
        const f32x4 v1 = ((const f32x4*)b1)[2 * i + hi];
        const f32x4 v2 = ((const f32x4*)b2)[2 * i + hi];
        #pragma unroll
        for (int o = 0; o < 4; ++o) {
            b1v[4 * i + o] = v1[o];
            b2v[4 * i + o] = v2[o];
        }
    }
    const float b3s = b3[0];
    #pragma unroll
    for (int r = 0; r < 16; ++r) b3v[r] = b3s;

    // ---- A-frags. phi(k)=swap(bit2,bit3) absorbs the C->B reg->slot
    // permutation (verified r6-r9, absmax 1.95e-3): applied to W2's k-rows
    // for L2, and to W3's k-slots for the new L3 MFMA pair. ----
    f16x8 a1, a2lo, a2hi, a3lo, a3hi;
    #pragma unroll
    for (int jj = 0; jj < 8; ++jj) {
        const int k  = 8 * hi + jj;
        a1[jj] = (k < WS) ? (_Float16)W1[k * HID + n] : (_Float16)0.0f;   // W1^T, K 10->16 pad
        const int kf = (k & 3) | ((k & 4) << 1) | ((k & 8) >> 1);         // phi: swap bits 2<->3
        a2lo[jj] = (_Float16)W2[kf * HID + n];
        a2hi[jj] = (_Float16)W2[(16 + kf) * HID + n];
        a3lo[jj] = (_Float16)W3[kf];          // broadcast over m (lane-n independent)
        a3hi[jj] = (_Float16)W3[16 + kf];
    }

    const float* rptr = returns + (size_t)blockIdx.x * T_LEN;
    float*       optr = out     + (size_t)blockIdx.x * T_LEN;

    // ---- branchless X loads, prefetched one group ahead.
    // lane window start ws; hi=0 needs elems 0..7, hi=1 needs elems 8,9.
    // uniform: 8B load at ws+8*hi (hi0: e0,e1 | hi1: e8,e9) + 24B at ws+2
    // (hi0: e2..e7 | hi1: in-bounds discard). Max addr = t-1 <= 4094. ----
    const int t0  = wid * GN + n;
    int ws_c = (t0 >= WS) ? (t0 - WS) : 0;
    float e2_c[2], v6_c[6];
    __builtin_memcpy(e2_c, &rptr[ws_c + 8 * hi], 8);
    __builtin_memcpy(v6_c, &rptr[ws_c + 2], 24);

    for (int g = wid; g < NGRP; g += NWAVE) {
        // prefetch next group's window bytes
        const int gn_ = (g + NWAVE < NGRP) ? (g + NWAVE) : g;
        const int tn  = gn_ * GN + n;
        const int wsn = (tn >= WS) ? (tn - WS) : 0;
        float e2_n[2], v6_n[6];
        __builtin_memcpy(e2_n, &rptr[wsn + 8 * hi], 8);
        __builtin_memcpy(v6_n, &rptr[wsn + 2], 24);

        // ---- assemble X B-frag (k = 8*hi + jj; k >= 10 zero) ----
        u32x4 xu;
        xu[0] = pack2u(e2_c[0], e2_c[1]);
        xu[1] = hi ? 0u : pack2u(v6_c[0], v6_c[1]);
        xu[2] = hi ? 0u : pack2u(v6_c[2], v6_c[3]);
        xu[3] = hi ? 0u : pack2u(v6_c[4], v6_c[5]);
        const f16x8 xb = __builtin_bit_cast(f16x8, xu);

        // ---- L1: bias rides the C-operand ----
        f32x16 d1 = __builtin_amdgcn_mfma_f32_32x32x16_f16(a1, xb, b1v, 0, 0, 0);

        // relu+pack: lane-local C-reg pairs ARE the next B-operand (phi in A)
        u32x4 p1lo, p1hi;
        #pragma unroll
        for (int i = 0; i < 4; ++i) {
            p1lo[i] = relu2(pack2u(d1[2 * i],     d1[2 * i + 1]));
            p1hi[i] = relu2(pack2u(d1[8 + 2 * i], d1[9 + 2 * i]));
        }

        // ---- L2 ----
        f32x16 d2 = __builtin_amdgcn_mfma_f32_32x32x16_f16(
                        a2lo, __builtin_bit_cast(f16x8, p1lo), b2v, 0, 0, 0);
        d2 = __builtin_amdgcn_mfma_f32_32x32x16_f16(
                        a2hi, __builtin_bit_cast(f16x8, p1hi), d2, 0, 0, 0);

        // relu+pack d2 the same way
        u32x4 p2lo, p2hi;
        #pragma unroll
        for (int i = 0; i < 4; ++i) {
            p2lo[i] = relu2(pack2u(d2[2 * i],     d2[2 * i + 1]));
            p2hi[i] = relu2(pack2u(d2[8 + 2 * i], d2[9 + 2 * i]));
        }

        // ---- L3: A = W3 broadcast to all rows -> every D reg = out[n]+b3 ----
        f32x16 d3 = __builtin_amdgcn_mfma_f32_32x32x16_f16(
                        a3lo, __builtin_bit_cast(f16x8, p2lo), b3v, 0, 0, 0);
        d3 = __builtin_amdgcn_mfma_f32_32x32x16_f16(
                        a3hi, __builtin_bit_cast(f16x8, p2hi), d3, 0, 0, 0);

        // ---- sigmoid epilogue; 32 coalesced stores from half 0 ----
        const float o = 0.5f * __builtin_amdgcn_rcpf(1.0f + __expf(-d3[0]));
        if (hi == 0)
            optr[g * GN + n] = o;

        #pragma unroll
        for (int i = 0; i < 2; ++i) e2_c[i] = e2_n[i];
        #pragma unroll
        for (int i = 0; i < 6; ++i) v6_c[i] = v6_n[i];
    }
}

extern "C" void kernel_launch(void* const* d_in, const int* in_sizes, int n_in,
                              void* d_out, int out_size, void* d_ws, size_t ws_size,
                              hipStream_t stream) {
    const float* returns = (const float*)d_in[0];
    const float* W1      = (const float*)d_in[1];
    const float* b1      = (const float*)d_in[2];
    const float* W2      = (const float*)d_in[3];
    const float* b2      = (const float*)d_in[4];
    const float* W3      = (const float*)d_in[5];
    const float* b3      = (const float*)d_in[6];
    float* out = (float*)d_out;

    const int B = out_size / T_LEN;   // 1024

    dim3 grid(B, 1, 1);               // one block per batch row; fully co-resident
    dim3 block(BDIM, 1, 1);
    hurst_row5<<<grid, block, 0, stream>>>(returns, W1, b1, W2, b2, W3, b3, out);
}

// Round 11
// 99.836 us; speedup vs baseline: 1.0683x; 1.0195x over previous
//
#include <hip/hip_runtime.h>
#include <math.h>

typedef _Float16 f16x8  __attribute__((ext_vector_type(8)));    // MFMA A/B operand (4 VGPRs)
typedef _Float16 h2v    __attribute__((ext_vector_type(2)));
typedef float    f32x16 __attribute__((ext_vector_type(16)));   // MFMA C/D operand (32x32)
typedef float    f32x4  __attribute__((ext_vector_type(4)));
typedef __fp16   h2a    __attribute__((ext_vector_type(2)));    // cvt_pkrtz result
typedef unsigned u32x4  __attribute__((ext_vector_type(4)));

#define WS    10
#define HID   32
#define BDIM  256
#define NWAVE 4
#define GN    32                  // points per group = MFMA N
#define T_LEN 4096
#define NGRP  (T_LEN / GN)        // 128 groups per row; 32 per wave; 16 ILP2-iters

__device__ inline unsigned pack2u(float a, float b) {
    h2a t = __builtin_amdgcn_cvt_pkrtz(a, b);   // a -> low16, b -> high16
    return __builtin_bit_cast(unsigned, t);
}
__device__ inline unsigned relu2(unsigned u) {  // v_pk_max_f16 with 0
    h2v x = __builtin_bit_cast(h2v, u);
    h2v z = {(_Float16)0.0f, (_Float16)0.0f};
    return __builtin_bit_cast(unsigned, __builtin_elementwise_max(x, z));
}

__device__ inline void load_win(const float* __restrict__ rptr, int t, int hi,
                                float e2[2], float v6[6]) {
    // lane window bytes are contiguous; 8B @ ws+8*hi covers (e0,e1|e8,e9),
    // 24B @ ws+2 covers e2..e7 (hi=1: in-bounds discard). 4B-aligned only.
    const int ws = (t >= WS) ? (t - WS) : 0;    // head points (t<10) reuse window 0
    __builtin_memcpy(e2, &rptr[ws + 8 * hi], 8);
    __builtin_memcpy(v6, &rptr[ws + 2], 24);
}

// Whole MLP for one 32-point group: 5 MFMAs + 20 pack/relu VALU.
// phi(k)=swap(bit2,bit3) on A-operand k-rows absorbs the C->B layout
// permutation between stages (verified r6-r10, absmax 1.95e-3).
__device__ inline float mlp_group(const float e2[2], const float v6[6], int hi,
                                  f16x8 a1, f16x8 a2lo, f16x8 a2hi,
                                  f16x8 a3lo, f16x8 a3hi,
                                  f32x16 b1v, f32x16 b2v, float corr)
{
    u32x4 xu;
    xu[0] = pack2u(e2[0], e2[1]);
    xu[1] = hi ? 0u : pack2u(v6[0], v6[1]);
    xu[2] = hi ? 0u : pack2u(v6[2], v6[3]);
    xu[3] = hi ? 0u : pack2u(v6[4], v6[5]);
    const f16x8 xb = __builtin_bit_cast(f16x8, xu);

    // L1 (bias rides C)
    f32x16 d1 = __builtin_amdgcn_mfma_f32_32x32x16_f16(a1, xb, b1v, 0, 0, 0);
    u32x4 p1lo, p1hi;
    #pragma unroll
    for (int i = 0; i < 4; ++i) {
        p1lo[i] = relu2(pack2u(d1[2 * i],     d1[2 * i + 1]));
        p1hi[i] = relu2(pack2u(d1[8 + 2 * i], d1[9 + 2 * i]));
    }
    // L2 (bias rides C)
    f32x16 d2 = __builtin_amdgcn_mfma_f32_32x32x16_f16(
                    a2lo, __builtin_bit_cast(f16x8, p1lo), b2v, 0, 0, 0);
    d2 = __builtin_amdgcn_mfma_f32_32x32x16_f16(
                    a2hi, __builtin_bit_cast(f16x8, p1hi), d2, 0, 0, 0);
    u32x4 p2lo, p2hi;
    #pragma unroll
    for (int i = 0; i < 4; ++i) {
        p2lo[i] = relu2(pack2u(d2[2 * i],     d2[2 * i + 1]));
        p2hi[i] = relu2(pack2u(d2[8 + 2 * i], d2[9 + 2 * i]));
    }
    // L3: A = W3 broadcast over rows; C-init reuses resident b2v (no extra
    // persistent vector), corrected by scalar corr = b3 - b2[4*hi] after.
    f32x16 d3 = __builtin_amdgcn_mfma_f32_32x32x16_f16(
                    a3lo, __builtin_bit_cast(f16x8, p2lo), b2v, 0, 0, 0);
    d3 = __builtin_amdgcn_mfma_f32_32x32x16_f16(
                    a3hi, __builtin_bit_cast(f16x8, p2hi), d3, 0, 0, 0);

    return 0.5f * __builtin_amdgcn_rcpf(1.0f + __expf(-(d3[0] + corr)));
}

// (256,3): reg cap ~170. Persistent: b1v+b2v (32) + 5 A-frags (20); two
// independent per-iteration chains (ILP=2) ~ +80 transient. Forcing 4
// waves (cap 128) would spill -> r2-style accvgpr traffic; 3x2 chains/SIMD
// beats 4x1.
__global__ __launch_bounds__(BDIM, 3)
void hurst_ilp2(const float* __restrict__ returns,
                const float* __restrict__ W1, const float* __restrict__ b1,
                const float* __restrict__ W2, const float* __restrict__ b2,
                const float* __restrict__ W3, const float* __restrict__ b3,
                float* __restrict__ out)
{
    const int tid  = threadIdx.x;
    const int wid  = tid >> 6;
    const int lane = tid & 63;
    const int n    = lane & 31;    // MFMA m (A-row) / n (B/C col)
    const int hi   = lane >> 5;    // k-half (A/B) / row-half (C/D)

    // ---- bias C-operands in C-layout: row(r)=(r&3)+8(r>>2)+4hi ----
    f32x16 b1v, b2v;
    #pragma unroll
    for (int i = 0; i < 4; ++i) {
        const f32x4 v1 = ((const f32x4*)b1)[2 * i + hi];
        const f32x4 v2 = ((const f32x4*)b2)[2 * i + hi];
        #pragma unroll
        for (int o = 0; o < 4; ++o) {
            b1v[4 * i + o] = v1[o];
            b2v[4 * i + o] = v2[o];
        }
    }
    const float corr = b3[0] - b2[4 * hi];   // undoes b2v[0] riding L3's C

    // ---- A-frags (phi-permuted where the operand follows a C-layout) ----
    f16x8 a1, a2lo, a2hi, a3lo, a3hi;
    #pragma unroll
    for (int jj = 0; jj < 8; ++jj) {
        const int k  = 8 * hi + jj;
        a1[jj] = (k < WS) ? (_Float16)W1[k * HID + n] : (_Float16)0.0f;   // W1^T, K 10->16 pad
        const int kf = (k & 3) | ((k & 4) << 1) | ((k & 8) >> 1);         // phi: swap bits 2<->3
        a2lo[jj] = (_Float16)W2[kf * HID + n];
        a2hi[jj] = (_Float16)W2[(16 + kf) * HID + n];
        a3lo[jj] = (_Float16)W3[kf];          // broadcast over m
        a3hi[jj] = (_Float16)W3[16 + kf];
    }

    const float* rptr = returns + (size_t)blockIdx.x * T_LEN;
    float*       optr = out     + (size_t)blockIdx.x * T_LEN;

    // ---- two chains/iteration (groups g, g+NWAVE), prefetched 1 iter ahead ----
    float e2a[2], v6a[6], e2b[2], v6b[6];
    load_win(rptr, wid * GN + n,           hi, e2a, v6a);
    load_win(rptr, (wid + NWAVE) * GN + n, hi, e2b, v6b);

    for (int g = wid; g < NGRP; g += 2 * NWAVE) {
        const int gp = (g + 2 * NWAVE < NGRP) ? (g + 2 * NWAVE) : g;
        float e2an[2], v6an[6], e2bn[2], v6bn[6];
        load_win(rptr, gp * GN + n,           hi, e2an, v6an);
        load_win(rptr, (gp + NWAVE) * GN + n, hi, e2bn, v6bn);

        const float oa = mlp_group(e2a, v6a, hi, a1, a2lo, a2hi, a3lo, a3hi, b1v, b2v, corr);
        const float ob = mlp_group(e2b, v6b, hi, a1, a2lo, a2hi, a3lo, a3hi, b1v, b2v, corr);

        if (hi == 0) {
            optr[g * GN + n]           = oa;
            optr[(g + NWAVE) * GN + n] = ob;
        }

        #pragma unroll
        for (int i = 0; i < 2; ++i) { e2a[i] = e2an[i]; e2b[i] = e2bn[i]; }
        #pragma unroll
        for (int i = 0; i < 6; ++i) { v6a[i] = v6an[i]; v6b[i] = v6bn[i]; }
    }
}

extern "C" void kernel_launch(void* const* d_in, const int* in_sizes, int n_in,
                              void* d_out, int out_size, void* d_ws, size_t ws_size,
                              hipStream_t stream) {
    const float* returns = (const float*)d_in[0];
    const float* W1      = (const float*)d_in[1];
    const float* b1      = (const float*)d_in[2];
    const float* W2      = (const float*)d_in[3];
    const float* b2      = (const float*)d_in[4];
    const float* W3      = (const float*)d_in[5];
    const float* b3      = (const float*)d_in[6];
    float* out = (float*)d_out;

    const int B = out_size / T_LEN;   // 1024

    dim3 grid(B, 1, 1);               // one block per batch row; fully co-resident
    dim3 block(BDIM, 1, 1);
    hurst_ilp2<<<grid, block, 0, stream>>>(returns, W1, b1, W2, b2, W3, b3, out);
}